// Round 12
// baseline (207.113 us; speedup 1.0000x reference)
//
#include <hip/hip_runtime.h>
#include <hip/hip_bf16.h>

// Problem constants
#define NB 2
#define NL 2048
#define ND 1024
#define NH 16
#define NDH 64
#define NM (NB*NL)   // 4096 rows total

typedef unsigned short u16;
typedef __attribute__((ext_vector_type(8))) short short8;   // 8 bf16 in 4 VGPRs
typedef __attribute__((ext_vector_type(4))) float floatx4;  // MFMA accumulator

#define QSCALE 0.180336880f   // 0.125 * log2(e): lets attention use exp2

// fp32 -> bf16 round-to-nearest-even (bit trick)
__device__ __forceinline__ u16 f2bf(float f) {
  union { float f; unsigned int u; } v; v.f = f;
  unsigned int r = v.u + 0x7FFF + ((v.u >> 16) & 1);
  return (u16)(r >> 16);
}

// async global->LDS 16B (m97 lever). LDS dest is wave-uniform base + lane*16.
__device__ __forceinline__ void async_cp16(const u16* lds, const u16* g) {
  __builtin_amdgcn_global_load_lds(
      (const __attribute__((address_space(1))) void*)g,
      (__attribute__((address_space(3))) void*)lds, 16, 0, 0);
}

// lane <-> lane^1 exchange on the VALU (DPP quad_perm [1,0,3,2]) — no LDS pipe
__device__ __forceinline__ float dpp_xor1_f(float v) {
  return __int_as_float(__builtin_amdgcn_mov_dpp(__float_as_int(v), 0xB1, 0xF, 0xF, true));
}

// pack two fp32 -> bf16x2 dword (HW pk-cvt where available)
__device__ __forceinline__ unsigned pk_bf16(float lo, float hi) {
  __hip_bfloat162 h2 = __float22bfloat162_rn(make_float2(lo, hi));
  return *(unsigned*)&h2;
}

// ---------------------------------------------------------------------------
// Pre-convert fp32 -> bf16: Wq,Wk,Wv,Wp (1M elems each) -> Wb, x (4M) -> xb.
// ---------------------------------------------------------------------------
__global__ __launch_bounds__(256)
void cvt_all(const float* __restrict__ wq, const float* __restrict__ wk,
             const float* __restrict__ wv, const float* __restrict__ wp,
             const float* __restrict__ x,
             u16* __restrict__ ow, u16* __restrict__ ox)
{
  const int per4 = ND * ND / 4;            // 262144 float4 per weight matrix
  const int tot  = 4 * per4 + NM * ND / 4; // + 1048576 for x
  for (int t = blockIdx.x * 256 + threadIdx.x; t < tot; t += gridDim.x * 256) {
    const float* src; uint2* dst; int off;
    if (t < 4 * per4) {
      int w = t >> 18; off = t & (per4 - 1);
      src = (w == 0) ? wq : (w == 1) ? wk : (w == 2) ? wv : wp;
      dst = (uint2*)(ow + (size_t)w * ND * ND);
    } else {
      off = t - 4 * per4; src = x; dst = (uint2*)ox;
    }
    float4 f = ((const float4*)src)[off];
    u16 h[4] = { f2bf(f.x), f2bf(f.y), f2bf(f.z), f2bf(f.w) };
    dst[off] = *(const uint2*)h;
  }
}

// ---------------------------------------------------------------------------
// Fused QKV GEMM: one dispatch, logical N = 3072 (z = n0>>10 selects set).
// Q pre-scaled by QSCALE. z==2 (V) writes DIRECTLY TRANSPOSED to VT
// [B,H,DH,L]: the 4 r2-consecutive acc values are l-consecutive -> one uint2
// of 4 packed bf16 per (i,j). Kills the separate vtrans pass (16 MB traffic).
// 128x128 tile, BK=32, 256 threads, MFMA 16x16x32.
// ---------------------------------------------------------------------------
#define BM 128
#define BN 128
#define BK 32
#define LDT 32   // LDS tile row stride in bf16 elems (contiguous for async cp)

__global__ __launch_bounds__(256)
void gemm_qkv(const u16* __restrict__ A, const u16* __restrict__ Wb,
              const float* __restrict__ bq, const float* __restrict__ bk,
              const float* __restrict__ bv,
              u16* __restrict__ Qb, u16* __restrict__ Kb, u16* __restrict__ VTb)
{
  const int n0g = blockIdx.x * BN;          // 0..2944
  const int z   = n0g >> 10;
  const int n0  = n0g & 1023;
  const u16* W    = Wb + (size_t)z * ND * ND;
  const float* Bi = (z == 0) ? bq : (z == 1) ? bk : bv;
  const float sc  = (z == 0) ? QSCALE : 1.0f;

  const int m0 = blockIdx.y * BM;
  const int tid  = threadIdx.x;
  const int lane = tid & 63;
  const int wave = tid >> 6;
  const int wm = (wave >> 1) * 64;
  const int wn = (wave & 1) * 64;
  const int quad = lane >> 4;
  const int l16  = lane & 15;

  __shared__ u16 As[BM * LDT];
  __shared__ u16 Bs[BN * LDT];

  floatx4 acc[4][4];
#pragma unroll
  for (int i = 0; i < 4; ++i)
#pragma unroll
    for (int j = 0; j < 4; ++j)
      acc[i][j] = (floatx4){0.f, 0.f, 0.f, 0.f};

  for (int k0 = 0; k0 < ND; k0 += BK) {
#pragma unroll
    for (int it = 0; it < 2; ++it) {
      int idx = tid + it * 256;            // 0..511
      int rr  = idx >> 2;                  // 0..127
      int c8  = (idx & 3) << 3;            // 0,8,16,24
      async_cp16(&Bs[idx * 8], &W[(size_t)(n0 + rr) * ND + k0 + c8]);
      async_cp16(&As[idx * 8], &A[(size_t)(m0 + rr) * ND + k0 + c8]);
    }
    __syncthreads();

    short8 af[4], bfr[4];
#pragma unroll
    for (int i = 0; i < 4; ++i)
      af[i] = *(const short8*)&As[(wm + i * 16 + l16) * LDT + quad * 8];
#pragma unroll
    for (int j = 0; j < 4; ++j)
      bfr[j] = *(const short8*)&Bs[(wn + j * 16 + l16) * LDT + quad * 8];

#pragma unroll
    for (int i = 0; i < 4; ++i)
#pragma unroll
      for (int j = 0; j < 4; ++j)
        acc[i][j] = __builtin_amdgcn_mfma_f32_16x16x32_bf16(af[i], bfr[j], acc[i][j], 0, 0, 0);
    __syncthreads();
  }

  // Epilogue. D map: row=(lane>>4)*4+r, col=lane&15.
  if (z == 2) {
    // V branch: transposed store. ncol = h*64+d; row m = b*NL+l.
#pragma unroll
    for (int j = 0; j < 4; ++j) {
      const int ncol = n0 + wn + j * 16 + l16;
      const int h2 = ncol >> 6, d = ncol & 63;
      const float bv2 = Bi[ncol];
#pragma unroll
      for (int i = 0; i < 4; ++i) {
        const int mbase = m0 + wm + i * 16 + quad * 4;   // 128-tile never crosses batch
        const int b2 = mbase >> 11, l = mbase & (NL - 1);
        uint2 val;
        val.x = pk_bf16(acc[i][j][0] + bv2, acc[i][j][1] + bv2);
        val.y = pk_bf16(acc[i][j][2] + bv2, acc[i][j][3] + bv2);
        *(uint2*)&VTb[((size_t)(b2 * NH + h2) * NDH + d) * NL + l] = val;
      }
    }
  } else {
    u16* C = (z == 0) ? Qb : Kb;
#pragma unroll
    for (int j = 0; j < 4; ++j) {
      const int ncol = n0 + wn + j * 16 + l16;
      const float bv2 = Bi[ncol];
#pragma unroll
      for (int i = 0; i < 4; ++i) {
        const int mbase = m0 + wm + i * 16 + quad * 4;
#pragma unroll
        for (int r2 = 0; r2 < 4; ++r2) {
          float v = (acc[i][j][r2] + bv2) * sc;
          C[(size_t)(mbase + r2) * ND + ncol] = f2bf(v);
        }
      }
    }
  }
}

// ---------------------------------------------------------------------------
// Output projection GEMM: C fp32 = A(bf16) W^T + bias. BN=64, BK=64:
// same MFMA:staging ratio as BK=32 but HALF the barriers (16 vs 32) and a
// deeper async queue per barrier. 512 blocks (2/CU).
// ---------------------------------------------------------------------------
#define BN2 64
#define BK2 64

__global__ __launch_bounds__(256)
void gemm_proj(const u16* __restrict__ A, const u16* __restrict__ W,
               const float* __restrict__ Bi, float* __restrict__ C)
{
  const int n0 = blockIdx.x * BN2;
  const int m0 = blockIdx.y * BM;
  const int tid  = threadIdx.x;
  const int lane = tid & 63;
  const int wave = tid >> 6;
  const int wm = (wave >> 1) * 64;
  const int wn = (wave & 1) * 32;
  const int quad = lane >> 4;
  const int l16  = lane & 15;

  __shared__ u16 As[BM * BK2];    // 16 KB
  __shared__ u16 Bs[BN2 * BK2];   // 8 KB

  floatx4 acc[4][2];
#pragma unroll
  for (int i = 0; i < 4; ++i)
#pragma unroll
    for (int j = 0; j < 2; ++j)
      acc[i][j] = (floatx4){0.f, 0.f, 0.f, 0.f};

  for (int k0 = 0; k0 < ND; k0 += BK2) {
#pragma unroll
    for (int it = 0; it < 4; ++it) {
      int idx = tid + it * 256;            // 0..1023
      int rr  = idx >> 3;                  // 0..127
      int c8  = (idx & 7) << 3;            // 0..56
      async_cp16(&As[idx * 8], &A[(size_t)(m0 + rr) * ND + k0 + c8]);
    }
#pragma unroll
    for (int it = 0; it < 2; ++it) {
      int idx = tid + it * 256;            // 0..511
      int rr  = idx >> 3;                  // 0..63
      int c8  = (idx & 7) << 3;
      async_cp16(&Bs[idx * 8], &W[(size_t)(n0 + rr) * ND + k0 + c8]);
    }
    __syncthreads();

#pragma unroll
    for (int kk = 0; kk < 2; ++kk) {
      short8 af[4], bfr[2];
#pragma unroll
      for (int i = 0; i < 4; ++i)
        af[i] = *(const short8*)&As[(wm + i * 16 + l16) * BK2 + kk * 32 + quad * 8];
#pragma unroll
      for (int j = 0; j < 2; ++j)
        bfr[j] = *(const short8*)&Bs[(wn + j * 16 + l16) * BK2 + kk * 32 + quad * 8];
#pragma unroll
      for (int i = 0; i < 4; ++i)
#pragma unroll
        for (int j = 0; j < 2; ++j)
          acc[i][j] = __builtin_amdgcn_mfma_f32_16x16x32_bf16(af[i], bfr[j], acc[i][j], 0, 0, 0);
    }
    __syncthreads();
  }

#pragma unroll
  for (int j = 0; j < 2; ++j) {
    const int ncol = n0 + wn + j * 16 + l16;
    const float bv2 = Bi[ncol];
#pragma unroll
    for (int i = 0; i < 4; ++i) {
      const int mbase = m0 + wm + i * 16 + quad * 4;
#pragma unroll
      for (int r2 = 0; r2 < 4; ++r2)
        C[(size_t)(mbase + r2) * ND + ncol] = acc[i][j][r2] + bv2;
    }
  }
}

// ---------------------------------------------------------------------------
// MFMA flash attention (r11 + diag hoist + global mask reads).
//  - no-max softmax via exp2 (Q pre-scaled by 0.125*log2e in gemm_qkv)
//  - K/VT staged by async_cp16 with xor-chunk swizzle (2-way aliasing, free)
//  - mask read directly from global each chunk (L1/L2-hot; VMEM pipe idle);
//    no Ms staging loop, less LDS
//  - diagonal chunk processed OUTSIDE the main loop: non-diag body has no
//    causal compare/cndmask at all
//  - P packed to LDS via float-DPP pair exchange + HW pk bf16 cvt
//  - l via MFMA ones-column. Y aliases Q.
// SCHEDULE (1024 blocks): xcd=t&7, r=t>>8, v=(t>>3)&31; bh=xcd*4+r (4 heads
// per XCD -> L2-resident K/V); qt={v,31-v,(v+16)%32,(15-v)%32}[r] (balanced).
// ---------------------------------------------------------------------------
#define KC 64
#define PSTR 72   // padded LDS row stride for Ps (bf16)

__global__ __launch_bounds__(256)
void attn_mfma(const u16* __restrict__ Q, const u16* __restrict__ K,
               const u16* __restrict__ VT, const int* __restrict__ msk,
               u16* __restrict__ Y)
{
  const int t = blockIdx.x;
  const int r = t >> 8;            // 0..3
  const int xcd = t & 7;
  const int v = (t >> 3) & 31;
  const int bh = xcd * 4 + r;
  const int qt = (r == 0) ? v
               : (r == 1) ? 31 - v
               : (r == 2) ? ((v + 16) & 31)
                          : ((15 - v) & 31);
  const int b = bh >> 4;
  const int h = bh & 15;
  const int q0 = qt * 64;
  const int tid  = threadIdx.x;
  const int lane = tid & 63;
  const int wave = tid >> 6;
  const int wq   = wave * 16;      // wave's q-row offset in tile
  const int quad = lane >> 4;
  const int l16  = lane & 15;

  __shared__ u16 Ks[KC * 64];      // [key][dim], chunk-swizzled, unpadded
  __shared__ u16 Vt[NDH * 64];     // [dim][key], chunk-swizzled, unpadded
  __shared__ u16 Ps[64][PSTR];     // [q_local][key]

  const u16* Kbase  = K  + (size_t)b * NL * ND + h * NDH;
  const u16* VTbase = VT + (size_t)(b * NH + h) * NDH * NL;
  const int* mbase  = msk + b * NL;

  // Q fragments (A-layout: m=l16, k=quad*8+j), pre-scaled in GEMM1.
  short8 qf[2];
#pragma unroll
  for (int kk = 0; kk < 2; ++kk)
    qf[kk] = *(const short8*)&Q[(size_t)(b * NL + q0 + wq + l16) * ND
                                + h * NDH + kk * 32 + quad * 8];

  // Constant ones B-fragment: B[n=l16][k] = (n==0) ? 1.0bf : 0
  short8 onesf;
  {
    const short ov = (l16 == 0) ? (short)0x3F80 : (short)0;
#pragma unroll
    for (int e = 0; e < 8; ++e) onesf[e] = ov;
  }

  floatx4 o[4];                    // output accum, un-normalized
#pragma unroll
  for (int ot = 0; ot < 4; ++ot) o[ot] = (floatx4){0.f, 0.f, 0.f, 0.f};
  floatx4 lacc = (floatx4){0.f, 0.f, 0.f, 0.f};   // col 0 holds row-sum l

  const int odd = l16 & 1;
  const int sw  = l16 & 7;         // frag-read swizzle key (row & 7)
  const int rowb = q0 + wq + quad * 4;

  auto chunk_body = [&](int k0, bool diag) {
    // ---- stage K + VT via async, chunk-swizzled (zero VALU pack) ----
#pragma unroll
    for (int p = 0; p < 2; ++p) {
      int sl = tid + p * 256;        // LDS 16B-slot index 0..511
      int rr = sl >> 3;              // row (key for K, dim for VT)
      int ch = (sl & 7) ^ (rr & 7);  // which global chunk goes to this slot
      async_cp16(&Ks[sl * 8], Kbase + (size_t)(k0 + rr) * ND + ch * 8);
      async_cp16(&Vt[sl * 8], VTbase + (size_t)rr * NL + k0 + ch * 8);
    }
    __syncthreads();

    // mask loads early (VMEM latency overlapped with QK^T MFMAs)
    int mm[4];
#pragma unroll
    for (int ct = 0; ct < 4; ++ct) mm[ct] = mbase[k0 + ct * 16 + l16];

    // ---- S = Q K^T  (C-layout: row=quad*4+r2, col=ct*16+l16) ----
    floatx4 sc[4];
#pragma unroll
    for (int ct = 0; ct < 4; ++ct) {
      const u16* krow = &Ks[(ct * 16 + l16) * 64];
      short8 kf0 = *(const short8*)(krow + ((quad ^ sw) << 3));
      short8 kf1 = *(const short8*)(krow + (((4 | quad) ^ sw) << 3));
      floatx4 a = (floatx4){0.f, 0.f, 0.f, 0.f};
      a = __builtin_amdgcn_mfma_f32_16x16x32_bf16(qf[0], kf0, a, 0, 0, 0);
      a = __builtin_amdgcn_mfma_f32_16x16x32_bf16(qf[1], kf1, a, 0, 0, 0);
      sc[ct] = a;
    }

    // ---- P = pad * [causal] * exp2(S); DPP-pair + pk-cvt b32 LDS writes ----
#pragma unroll
    for (int ct = 0; ct < 4; ++ct) {
      const float pmul = (float)mm[ct];
      float pv[4];
#pragma unroll
      for (int r2 = 0; r2 < 4; ++r2) {
        float p = pmul * __builtin_amdgcn_exp2f(sc[ct][r2]);
        if (diag) {
          const int col = k0 + ct * 16 + l16;
          p = (col > rowb + r2) ? 0.f : p;
        }
        pv[r2] = p;
      }
      float nb0 = dpp_xor1_f(pv[0]), nb1 = dpp_xor1_f(pv[1]);
      float nb2 = dpp_xor1_f(pv[2]), nb3 = dpp_xor1_f(pv[3]);
      const int colb  = ct * 16 + (l16 & ~1);
      const int row01 = wq + quad * 4 + odd;
      unsigned d01 = odd ? pk_bf16(nb1, pv[1]) : pk_bf16(pv[0], nb0);
      unsigned d23 = odd ? pk_bf16(nb3, pv[3]) : pk_bf16(pv[2], nb2);
      *(unsigned*)&Ps[row01][colb]     = d01;
      *(unsigned*)&Ps[row01 + 2][colb] = d23;
    }

    // ---- O += P V ; l += P * ones ----
#pragma unroll
    for (int kk = 0; kk < 2; ++kk) {
      short8 pf = *(const short8*)&Ps[wq + l16][kk * 32 + quad * 8];
#pragma unroll
      for (int ot = 0; ot < 4; ++ot) {
        const u16* vrow = &Vt[(ot * 16 + l16) * 64];
        short8 vf = *(const short8*)(vrow + ((((kk << 2) | quad) ^ sw) << 3));
        o[ot] = __builtin_amdgcn_mfma_f32_16x16x32_bf16(pf, vf, o[ot], 0, 0, 0);
      }
      lacc = __builtin_amdgcn_mfma_f32_16x16x32_bf16(pf, onesf, lacc, 0, 0, 0);
    }
    __syncthreads();   // protect Ks/Vt before restaging
  };

  for (int kc = 0; kc < qt; ++kc) chunk_body(kc * KC, false);
  chunk_body(qt * KC, true);

  // ---- epilogue: O / l -> Y (aliases Q; our rows only, reads done) ----
  float inv[4];
#pragma unroll
  for (int r2 = 0; r2 < 4; ++r2) {
    const float l = __shfl(lacc[r2], quad << 4);   // col 0 of the l-tile
    inv[r2] = 1.0f / l;
  }
#pragma unroll
  for (int ot = 0; ot < 4; ++ot)
#pragma unroll
    for (int r2 = 0; r2 < 4; ++r2) {
      const int row = q0 + wq + quad * 4 + r2;
      Y[(size_t)(b * NL + row) * ND + h * NDH + ot * 16 + l16] = f2bf(o[ot][r2] * inv[r2]);
    }
}

// ---------------------------------------------------------------------------
extern "C" void kernel_launch(void* const* d_in, const int* in_sizes, int n_in,
                              void* d_out, int out_size, void* d_ws, size_t ws_size,
                              hipStream_t stream) {
  const float* x  = (const float*)d_in[0];
  const int*   m  = (const int*)d_in[1];
  const float* Wq = (const float*)d_in[2];
  const float* bq = (const float*)d_in[3];
  const float* Wk = (const float*)d_in[4];
  const float* bk = (const float*)d_in[5];
  const float* Wv = (const float*)d_in[6];
  const float* bv = (const float*)d_in[7];
  const float* Wp = (const float*)d_in[8];
  const float* bp = (const float*)d_in[9];
  float* out = (float*)d_out;

  // Workspace (32 MiB): Q|Y alias (8) + K (8) + [V region unused] + Wb (8)
  // d_out (16 MiB fp32) moonlights: xb (bf16 x, first 8 MiB) + VTb (bf16 V^T,
  // second 8 MiB, written directly by gemm_qkv). Both dead before the final
  // proj GEMM overwrites d_out.
  const size_t per = (size_t)NM * ND;
  u16* Qb = (u16*)d_ws;
  u16* Kb = Qb + per;
  u16* Wb = Kb + 2 * per;          // skip unused V slot; 4 * ND*ND bf16
  u16* Yb = Qb;                    // alias
  u16* xb = (u16*)d_out;
  u16* VTb = xb + per;

  // 0) fp32 -> bf16 for weights and x
  cvt_all<<<2048, 256, 0, stream>>>(Wq, Wk, Wv, Wp, x, Wb, xb);

  // 1) QKV projections, single fused dispatch (Q pre-scaled; V written as VT)
  gemm_qkv<<<dim3(3 * ND / BN, NM / BM), 256, 0, stream>>>(
      xb, Wb, bq, bk, bv, Qb, Kb, VTb);

  // 2) MFMA flash attention (Y aliases Q)
  attn_mfma<<<1024, 256, 0, stream>>>(Qb, Kb, VTb, m, Yb);

  // 3) Output projection (BN=64, BK=64)
  const u16* Wpb = Wb + 3 * (size_t)ND * ND;
  gemm_proj<<<dim3(ND / BN2, NM / BM), 256, 0, stream>>>(Yb, Wpb, bp, out);
}

// Round 13
// 201.776 us; speedup vs baseline: 1.0265x; 1.0265x over previous
//
#include <hip/hip_runtime.h>
#include <hip/hip_bf16.h>

// Problem constants
#define NB 2
#define NL 2048
#define ND 1024
#define NH 16
#define NDH 64
#define NM (NB*NL)   // 4096 rows total

typedef unsigned short u16;
typedef __attribute__((ext_vector_type(8))) short short8;   // 8 bf16 in 4 VGPRs
typedef __attribute__((ext_vector_type(4))) float floatx4;  // MFMA accumulator

#define QSCALE 0.180336880f   // 0.125 * log2(e): lets attention use exp2

// fp32 -> bf16 round-to-nearest-even (bit trick)
__device__ __forceinline__ u16 f2bf(float f) {
  union { float f; unsigned int u; } v; v.f = f;
  unsigned int r = v.u + 0x7FFF + ((v.u >> 16) & 1);
  return (u16)(r >> 16);
}

// async global->LDS 16B. LDS dest must be linear in lane; global side may be
// a per-lane gather (verified r11: swizzled-source staging is correct+fast).
__device__ __forceinline__ void async_cp16(const u16* lds, const u16* g) {
  __builtin_amdgcn_global_load_lds(
      (const __attribute__((address_space(1))) void*)g,
      (__attribute__((address_space(3))) void*)lds, 16, 0, 0);
}

// lane <-> lane^1 exchange on the VALU (DPP quad_perm [1,0,3,2]) — no LDS pipe
__device__ __forceinline__ float dpp_xor1_f(float v) {
  return __int_as_float(__builtin_amdgcn_mov_dpp(__float_as_int(v), 0xB1, 0xF, 0xF, true));
}

// pack two fp32 -> bf16x2 dword
__device__ __forceinline__ unsigned pk_bf16(float lo, float hi) {
  __hip_bfloat162 h2 = __float22bfloat162_rn(make_float2(lo, hi));
  return *(unsigned*)&h2;
}

// ---------------------------------------------------------------------------
// Pre-convert fp32 -> bf16: Wq,Wk,Wv,Wp (1M elems each) -> Wb, x (4M) -> xb.
// ---------------------------------------------------------------------------
__global__ __launch_bounds__(256)
void cvt_all(const float* __restrict__ wq, const float* __restrict__ wk,
             const float* __restrict__ wv, const float* __restrict__ wp,
             const float* __restrict__ x,
             u16* __restrict__ ow, u16* __restrict__ ox)
{
  const int per4 = ND * ND / 4;            // 262144 float4 per weight matrix
  const int tot  = 4 * per4 + NM * ND / 4; // + 1048576 for x
  for (int t = blockIdx.x * 256 + threadIdx.x; t < tot; t += gridDim.x * 256) {
    const float* src; uint2* dst; int off;
    if (t < 4 * per4) {
      int w = t >> 18; off = t & (per4 - 1);
      src = (w == 0) ? wq : (w == 1) ? wk : (w == 2) ? wv : wp;
      dst = (uint2*)(ow + (size_t)w * ND * ND);
    } else {
      off = t - 4 * per4; src = x; dst = (uint2*)ox;
    }
    float4 f = ((const float4*)src)[off];
    u16 h[4] = { f2bf(f.x), f2bf(f.y), f2bf(f.z), f2bf(f.w) };
    dst[off] = *(const uint2*)h;
  }
}

// ---------------------------------------------------------------------------
// Fused QKV GEMM (BK=64, swizzled staging): one dispatch, logical N = 3072
// (z = n0>>10). Q pre-scaled by QSCALE. Natural-layout stores (coalesced);
// V transposed in a separate pass (fused-transpose scatter was the r12
// regression). Staging: global chunk ch=(idx&7)^(rr&7) -> linear LDS slot;
// frag reads use chunk (kk*4+quad)^ (l16&7) -> 2-way bank aliasing (free).
// BK=64 halves barrier drains vs BK=32 (16 iters vs 32); LDS 32 KB.
// ---------------------------------------------------------------------------
#define BM 128
#define BN 128
#define BKQ 64

__global__ __launch_bounds__(256)
void gemm_qkv(const u16* __restrict__ A, const u16* __restrict__ Wb,
              const float* __restrict__ bq, const float* __restrict__ bk,
              const float* __restrict__ bv,
              u16* __restrict__ Qb, u16* __restrict__ Kb, u16* __restrict__ Vb)
{
  const int n0g = blockIdx.x * BN;          // 0..2944
  const int z   = n0g >> 10;
  const int n0  = n0g & 1023;
  const u16* W    = Wb + (size_t)z * ND * ND;
  const float* Bi = (z == 0) ? bq : (z == 1) ? bk : bv;
  u16* C          = (z == 0) ? Qb : (z == 1) ? Kb : Vb;
  const float sc  = (z == 0) ? QSCALE : 1.0f;

  const int m0 = blockIdx.y * BM;
  const int tid  = threadIdx.x;
  const int lane = tid & 63;
  const int wave = tid >> 6;
  const int wm = (wave >> 1) * 64;
  const int wn = (wave & 1) * 64;
  const int quad = lane >> 4;
  const int l16  = lane & 15;
  const int sw   = l16 & 7;

  __shared__ u16 As[BM * BKQ];   // 16 KB
  __shared__ u16 Bs[BN * BKQ];   // 16 KB

  floatx4 acc[4][4];
#pragma unroll
  for (int i = 0; i < 4; ++i)
#pragma unroll
    for (int j = 0; j < 4; ++j)
      acc[i][j] = (floatx4){0.f, 0.f, 0.f, 0.f};

  for (int k0 = 0; k0 < ND; k0 += BKQ) {
#pragma unroll
    for (int it = 0; it < 4; ++it) {
      int idx = tid + it * 256;            // 0..1023
      int rr  = idx >> 3;                  // 0..127
      int ch  = (idx & 7) ^ (rr & 7);      // swizzled global chunk
      async_cp16(&As[idx * 8], &A[(size_t)(m0 + rr) * ND + k0 + ch * 8]);
      async_cp16(&Bs[idx * 8], &W[(size_t)(n0 + rr) * ND + k0 + ch * 8]);
    }
    __syncthreads();

#pragma unroll
    for (int kk = 0; kk < 2; ++kk) {
      const int cq = ((kk << 2) | quad) ^ sw;
      short8 af[4], bfr[4];
#pragma unroll
      for (int i = 0; i < 4; ++i)
        af[i] = *(const short8*)&As[((wm + i * 16 + l16) * 8 + cq) * 8];
#pragma unroll
      for (int j = 0; j < 4; ++j)
        bfr[j] = *(const short8*)&Bs[((wn + j * 16 + l16) * 8 + cq) * 8];
#pragma unroll
      for (int i = 0; i < 4; ++i)
#pragma unroll
        for (int j = 0; j < 4; ++j)
          acc[i][j] = __builtin_amdgcn_mfma_f32_16x16x32_bf16(af[i], bfr[j], acc[i][j], 0, 0, 0);
    }
    __syncthreads();
  }

  // Epilogue. D map: row=(lane>>4)*4+r, col=lane&15.
#pragma unroll
  for (int j = 0; j < 4; ++j) {
    const int ncol = n0 + wn + j * 16 + l16;
    const float bv2 = Bi[ncol];
#pragma unroll
    for (int i = 0; i < 4; ++i) {
      const int mbase = m0 + wm + i * 16 + quad * 4;
#pragma unroll
      for (int r2 = 0; r2 < 4; ++r2) {
        float v = (acc[i][j][r2] + bv2) * sc;
        C[(size_t)(mbase + r2) * ND + ncol] = f2bf(v);
      }
    }
  }
}

// ---------------------------------------------------------------------------
// Output projection GEMM (BN=64, BK=64, swizzled staging): C fp32.
// 512 blocks (2/CU). 16 barrier iters.
// ---------------------------------------------------------------------------
#define BN2 64
#define BK2 64

__global__ __launch_bounds__(256)
void gemm_proj(const u16* __restrict__ A, const u16* __restrict__ W,
               const float* __restrict__ Bi, float* __restrict__ C)
{
  const int n0 = blockIdx.x * BN2;
  const int m0 = blockIdx.y * BM;
  const int tid  = threadIdx.x;
  const int lane = tid & 63;
  const int wave = tid >> 6;
  const int wm = (wave >> 1) * 64;
  const int wn = (wave & 1) * 32;
  const int quad = lane >> 4;
  const int l16  = lane & 15;
  const int sw   = l16 & 7;

  __shared__ u16 As[BM * BK2];    // 16 KB
  __shared__ u16 Bs[BN2 * BK2];   // 8 KB

  floatx4 acc[4][2];
#pragma unroll
  for (int i = 0; i < 4; ++i)
#pragma unroll
    for (int j = 0; j < 2; ++j)
      acc[i][j] = (floatx4){0.f, 0.f, 0.f, 0.f};

  for (int k0 = 0; k0 < ND; k0 += BK2) {
#pragma unroll
    for (int it = 0; it < 4; ++it) {
      int idx = tid + it * 256;            // 0..1023
      int rr  = idx >> 3;                  // 0..127
      int ch  = (idx & 7) ^ (rr & 7);
      async_cp16(&As[idx * 8], &A[(size_t)(m0 + rr) * ND + k0 + ch * 8]);
    }
#pragma unroll
    for (int it = 0; it < 2; ++it) {
      int idx = tid + it * 256;            // 0..511
      int rr  = idx >> 3;                  // 0..63
      int ch  = (idx & 7) ^ (rr & 7);
      async_cp16(&Bs[idx * 8], &W[(size_t)(n0 + rr) * ND + k0 + ch * 8]);
    }
    __syncthreads();

#pragma unroll
    for (int kk = 0; kk < 2; ++kk) {
      const int cq = ((kk << 2) | quad) ^ sw;
      short8 af[4], bfr[2];
#pragma unroll
      for (int i = 0; i < 4; ++i)
        af[i] = *(const short8*)&As[((wm + i * 16 + l16) * 8 + cq) * 8];
#pragma unroll
      for (int j = 0; j < 2; ++j)
        bfr[j] = *(const short8*)&Bs[((wn + j * 16 + l16) * 8 + cq) * 8];
#pragma unroll
      for (int i = 0; i < 4; ++i)
#pragma unroll
        for (int j = 0; j < 2; ++j)
          acc[i][j] = __builtin_amdgcn_mfma_f32_16x16x32_bf16(af[i], bfr[j], acc[i][j], 0, 0, 0);
    }
    __syncthreads();
  }

#pragma unroll
  for (int j = 0; j < 2; ++j) {
    const int ncol = n0 + wn + j * 16 + l16;
    const float bv2 = Bi[ncol];
#pragma unroll
    for (int i = 0; i < 4; ++i) {
      const int mbase = m0 + wm + i * 16 + quad * 4;
#pragma unroll
      for (int r2 = 0; r2 < 4; ++r2)
        C[(size_t)(mbase + r2) * ND + ncol] = acc[i][j][r2] + bv2;
    }
  }
}

// ---------------------------------------------------------------------------
// V transpose: V [B,L,H,DH] bf16 -> VT [B,H,DH,L] bf16. 64x64 tiles via LDS.
// Fully-coalesced uint4 loads and stores (this is what r12's fused-epilogue
// scatter lost). ~4 µs.
// ---------------------------------------------------------------------------
#define TSTR 66
__global__ __launch_bounds__(256)
void vtrans(const u16* __restrict__ V, u16* __restrict__ VT)
{
  const int lt = blockIdx.x;        // l tile 0..31
  const int bh = blockIdx.y;
  const int b = bh >> 4, h = bh & 15;
  const int l0 = lt * 64;
  const int tid = threadIdx.x;
  __shared__ u16 Ls[64][TSTR];
#pragma unroll
  for (int p = 0; p < 2; ++p) {
    int idx = tid + p * 256;
    int r = idx >> 3, c = (idx & 7) << 3;
    *(uint4*)&Ls[r][c] = *(const uint4*)&V[(size_t)(b * NL + l0 + r) * ND + h * NDH + c];
  }
  __syncthreads();
#pragma unroll
  for (int p = 0; p < 2; ++p) {
    int idx = tid + p * 256;
    int lg = idx & 7, d = idx >> 3;   // lg = l-subgroup, d = dim 0..63
    u16 tb[8];
#pragma unroll
    for (int e = 0; e < 8; ++e) tb[e] = Ls[lg * 8 + e][d];
    *(uint4*)&VT[((size_t)(b * NH + h) * NDH + d) * NL + l0 + lg * 8] = *(const uint4*)tb;
  }
}

// ---------------------------------------------------------------------------
// MFMA flash attention (unchanged from r12 — measured 53.6 µs).
// SCHEDULE (1024 blocks): xcd=t&7, r=t>>8, v=(t>>3)&31; bh=xcd*4+r (4 heads
// per XCD -> L2-resident K/V); qt={v,31-v,(v+16)%32,(15-v)%32}[r] (balanced).
// ---------------------------------------------------------------------------
#define KC 64
#define PSTR 72   // padded LDS row stride for Ps (bf16)

__global__ __launch_bounds__(256)
void attn_mfma(const u16* __restrict__ Q, const u16* __restrict__ K,
               const u16* __restrict__ VT, const int* __restrict__ msk,
               u16* __restrict__ Y)
{
  const int t = blockIdx.x;
  const int r = t >> 8;            // 0..3
  const int xcd = t & 7;
  const int v = (t >> 3) & 31;
  const int bh = xcd * 4 + r;
  const int qt = (r == 0) ? v
               : (r == 1) ? 31 - v
               : (r == 2) ? ((v + 16) & 31)
                          : ((15 - v) & 31);
  const int b = bh >> 4;
  const int h = bh & 15;
  const int q0 = qt * 64;
  const int tid  = threadIdx.x;
  const int lane = tid & 63;
  const int wave = tid >> 6;
  const int wq   = wave * 16;      // wave's q-row offset in tile
  const int quad = lane >> 4;
  const int l16  = lane & 15;

  __shared__ u16 Ks[KC * 64];      // [key][dim], chunk-swizzled, unpadded
  __shared__ u16 Vt[NDH * 64];     // [dim][key], chunk-swizzled, unpadded
  __shared__ u16 Ps[64][PSTR];     // [q_local][key]

  const u16* Kbase  = K  + (size_t)b * NL * ND + h * NDH;
  const u16* VTbase = VT + (size_t)(b * NH + h) * NDH * NL;
  const int* mbase  = msk + b * NL;

  // Q fragments (A-layout: m=l16, k=quad*8+j), pre-scaled in GEMM1.
  short8 qf[2];
#pragma unroll
  for (int kk = 0; kk < 2; ++kk)
    qf[kk] = *(const short8*)&Q[(size_t)(b * NL + q0 + wq + l16) * ND
                                + h * NDH + kk * 32 + quad * 8];

  // Constant ones B-fragment: B[n=l16][k] = (n==0) ? 1.0bf : 0
  short8 onesf;
  {
    const short ov = (l16 == 0) ? (short)0x3F80 : (short)0;
#pragma unroll
    for (int e = 0; e < 8; ++e) onesf[e] = ov;
  }

  floatx4 o[4];                    // output accum, un-normalized
#pragma unroll
  for (int ot = 0; ot < 4; ++ot) o[ot] = (floatx4){0.f, 0.f, 0.f, 0.f};
  floatx4 lacc = (floatx4){0.f, 0.f, 0.f, 0.f};   // col 0 holds row-sum l

  const int odd = l16 & 1;
  const int sw  = l16 & 7;         // frag-read swizzle key (row & 7)
  const int rowb = q0 + wq + quad * 4;

  auto chunk_body = [&](int k0, bool diag) {
    // ---- stage K + VT via async, chunk-swizzled (zero VALU pack) ----
#pragma unroll
    for (int p = 0; p < 2; ++p) {
      int sl = tid + p * 256;        // LDS 16B-slot index 0..511
      int rr = sl >> 3;              // row (key for K, dim for VT)
      int ch = (sl & 7) ^ (rr & 7);  // which global chunk goes to this slot
      async_cp16(&Ks[sl * 8], Kbase + (size_t)(k0 + rr) * ND + ch * 8);
      async_cp16(&Vt[sl * 8], VTbase + (size_t)rr * NL + k0 + ch * 8);
    }
    __syncthreads();

    // mask loads early (VMEM latency overlapped with QK^T MFMAs)
    int mm[4];
#pragma unroll
    for (int ct = 0; ct < 4; ++ct) mm[ct] = mbase[k0 + ct * 16 + l16];

    // ---- S = Q K^T  (C-layout: row=quad*4+r2, col=ct*16+l16) ----
    floatx4 sc[4];
#pragma unroll
    for (int ct = 0; ct < 4; ++ct) {
      const u16* krow = &Ks[(ct * 16 + l16) * 64];
      short8 kf0 = *(const short8*)(krow + ((quad ^ sw) << 3));
      short8 kf1 = *(const short8*)(krow + (((4 | quad) ^ sw) << 3));
      floatx4 a = (floatx4){0.f, 0.f, 0.f, 0.f};
      a = __builtin_amdgcn_mfma_f32_16x16x32_bf16(qf[0], kf0, a, 0, 0, 0);
      a = __builtin_amdgcn_mfma_f32_16x16x32_bf16(qf[1], kf1, a, 0, 0, 0);
      sc[ct] = a;
    }

    // ---- P = pad * [causal] * exp2(S); DPP-pair + pk-cvt b32 LDS writes ----
#pragma unroll
    for (int ct = 0; ct < 4; ++ct) {
      const float pmul = (float)mm[ct];
      float pv[4];
#pragma unroll
      for (int r2 = 0; r2 < 4; ++r2) {
        float p = pmul * __builtin_amdgcn_exp2f(sc[ct][r2]);
        if (diag) {
          const int col = k0 + ct * 16 + l16;
          p = (col > rowb + r2) ? 0.f : p;
        }
        pv[r2] = p;
      }
      float nb0 = dpp_xor1_f(pv[0]), nb1 = dpp_xor1_f(pv[1]);
      float nb2 = dpp_xor1_f(pv[2]), nb3 = dpp_xor1_f(pv[3]);
      const int colb  = ct * 16 + (l16 & ~1);
      const int row01 = wq + quad * 4 + odd;
      unsigned d01 = odd ? pk_bf16(nb1, pv[1]) : pk_bf16(pv[0], nb0);
      unsigned d23 = odd ? pk_bf16(nb3, pv[3]) : pk_bf16(pv[2], nb2);
      *(unsigned*)&Ps[row01][colb]     = d01;
      *(unsigned*)&Ps[row01 + 2][colb] = d23;
    }

    // ---- O += P V ; l += P * ones ----
#pragma unroll
    for (int kk = 0; kk < 2; ++kk) {
      short8 pf = *(const short8*)&Ps[wq + l16][kk * 32 + quad * 8];
#pragma unroll
      for (int ot = 0; ot < 4; ++ot) {
        const u16* vrow = &Vt[(ot * 16 + l16) * 64];
        short8 vf = *(const short8*)(vrow + ((((kk << 2) | quad) ^ sw) << 3));
        o[ot] = __builtin_amdgcn_mfma_f32_16x16x32_bf16(pf, vf, o[ot], 0, 0, 0);
      }
      lacc = __builtin_amdgcn_mfma_f32_16x16x32_bf16(pf, onesf, lacc, 0, 0, 0);
    }
    __syncthreads();   // protect Ks/Vt before restaging
  };

  for (int kc = 0; kc < qt; ++kc) chunk_body(kc * KC, false);
  chunk_body(qt * KC, true);

  // ---- epilogue: O / l -> Y (aliases Q; our rows only, reads done) ----
  float inv[4];
#pragma unroll
  for (int r2 = 0; r2 < 4; ++r2) {
    const float l = __shfl(lacc[r2], quad << 4);   // col 0 of the l-tile
    inv[r2] = 1.0f / l;
  }
#pragma unroll
  for (int ot = 0; ot < 4; ++ot)
#pragma unroll
    for (int r2 = 0; r2 < 4; ++r2) {
      const int row = q0 + wq + quad * 4 + r2;
      Y[(size_t)(b * NL + row) * ND + h * NDH + ot * 16 + l16] = f2bf(o[ot][r2] * inv[r2]);
    }
}

// ---------------------------------------------------------------------------
extern "C" void kernel_launch(void* const* d_in, const int* in_sizes, int n_in,
                              void* d_out, int out_size, void* d_ws, size_t ws_size,
                              hipStream_t stream) {
  const float* x  = (const float*)d_in[0];
  const int*   m  = (const int*)d_in[1];
  const float* Wq = (const float*)d_in[2];
  const float* bq = (const float*)d_in[3];
  const float* Wk = (const float*)d_in[4];
  const float* bk = (const float*)d_in[5];
  const float* Wv = (const float*)d_in[6];
  const float* bv = (const float*)d_in[7];
  const float* Wp = (const float*)d_in[8];
  const float* bp = (const float*)d_in[9];
  float* out = (float*)d_out;

  // Workspace (32 MiB): Q|Y alias (8) + K (8) + V (8) + Wb bf16 x4 (8)
  // d_out (16 MiB fp32) moonlights: xb (bf16 x, first 8 MiB) + VTb (bf16 V^T,
  // second 8 MiB). Both dead before the final proj GEMM overwrites d_out.
  const size_t per = (size_t)NM * ND;
  u16* Qb = (u16*)d_ws;
  u16* Kb = Qb + per;
  u16* Vb = Kb + per;
  u16* Wb = Vb + per;              // 4 * ND*ND bf16, contiguous
  u16* Yb = Qb;                    // alias
  u16* xb = (u16*)d_out;
  u16* VTb = xb + per;

  // 0) fp32 -> bf16 for weights and x
  cvt_all<<<2048, 256, 0, stream>>>(Wq, Wk, Wv, Wp, x, Wb, xb);

  // 1) QKV projections, single fused dispatch (Q pre-scaled by QSCALE)
  gemm_qkv<<<dim3(3 * ND / BN, NM / BM), 256, 0, stream>>>(
      xb, Wb, bq, bk, bv, Qb, Kb, Vb);

  // 1b) V -> VT (coalesced transpose pass)
  vtrans<<<dim3(NL / 64, NB * NH), 256, 0, stream>>>(Vb, VTb);

  // 2) MFMA flash attention (Y aliases Q)
  attn_mfma<<<1024, 256, 0, stream>>>(Qb, Kb, VTb, m, Yb);

  // 3) Output projection (BN=64, BK=64, swizzled)
  const u16* Wpb = Wb + 3 * (size_t)ND * ND;
  gemm_proj<<<dim3(ND / BN2, NM / BM), 256, 0, stream>>>(Yb, Wpb, bp, out);
}

// Round 14
// 192.478 us; speedup vs baseline: 1.0760x; 1.0483x over previous
//
#include <hip/hip_runtime.h>
#include <hip/hip_bf16.h>

// Problem constants
#define NB 2
#define NL 2048
#define ND 1024
#define NH 16
#define NDH 64
#define NM (NB*NL)   // 4096 rows total

typedef unsigned short u16;
typedef __attribute__((ext_vector_type(8))) short short8;   // 8 bf16 in 4 VGPRs
typedef __attribute__((ext_vector_type(4))) float floatx4;  // MFMA accumulator

#define QSCALE 0.180336880f   // 0.125 * log2(e): lets attention use exp2

__device__ __forceinline__ float bf2f(u16 u) {
  union { unsigned int ui; float f; } w;
  w.ui = ((unsigned int)u) << 16;
  return w.f;
}

// fp32 -> bf16 round-to-nearest-even (bit trick)
__device__ __forceinline__ u16 f2bf(float f) {
  union { float f; unsigned int u; } v; v.f = f;
  unsigned int r = v.u + 0x7FFF + ((v.u >> 16) & 1);
  return (u16)(r >> 16);
}

// async global->LDS 16B
__device__ __forceinline__ void async_cp16(const u16* lds, const u16* g) {
  __builtin_amdgcn_global_load_lds(
      (const __attribute__((address_space(1))) void*)g,
      (__attribute__((address_space(3))) void*)lds, 16, 0, 0);
}

// lane <-> lane^1 exchange on the VALU (DPP quad_perm [1,0,3,2])
__device__ __forceinline__ float dpp_xor1_f(float v) {
  return __int_as_float(__builtin_amdgcn_mov_dpp(__float_as_int(v), 0xB1, 0xF, 0xF, true));
}

// pack two fp32 -> bf16x2 dword
__device__ __forceinline__ unsigned pk_bf16(float lo, float hi) {
  __hip_bfloat162 h2 = __float22bfloat162_rn(make_float2(lo, hi));
  return *(unsigned*)&h2;
}

// ---------------------------------------------------------------------------
// Pre-convert fp32 -> bf16: Wq,Wk,Wv,Wp -> Wb, x -> xb.
// ---------------------------------------------------------------------------
__global__ __launch_bounds__(256)
void cvt_all(const float* __restrict__ wq, const float* __restrict__ wk,
             const float* __restrict__ wv, const float* __restrict__ wp,
             const float* __restrict__ x,
             u16* __restrict__ ow, u16* __restrict__ ox)
{
  const int per4 = ND * ND / 4;
  const int tot  = 4 * per4 + NM * ND / 4;
  for (int t = blockIdx.x * 256 + threadIdx.x; t < tot; t += gridDim.x * 256) {
    const float* src; uint2* dst; int off;
    if (t < 4 * per4) {
      int w = t >> 18; off = t & (per4 - 1);
      src = (w == 0) ? wq : (w == 1) ? wk : (w == 2) ? wv : wp;
      dst = (uint2*)(ow + (size_t)w * ND * ND);
    } else {
      off = t - 4 * per4; src = x; dst = (uint2*)ox;
    }
    float4 f = ((const float4*)src)[off];
    u16 h[4] = { f2bf(f.x), f2bf(f.y), f2bf(f.z), f2bf(f.w) };
    dst[off] = *(const uint2*)h;
  }
}

// ---------------------------------------------------------------------------
// Fused QKV GEMM (r11 proven form): BK=32, LDT=32, async staging, 16 KB LDS.
// ---------------------------------------------------------------------------
#define BM 128
#define BN 128
#define BK 32
#define LDT 32

__global__ __launch_bounds__(256)
void gemm_qkv(const u16* __restrict__ A, const u16* __restrict__ Wb,
              const float* __restrict__ bq, const float* __restrict__ bk,
              const float* __restrict__ bv,
              u16* __restrict__ Qb, u16* __restrict__ Kb, u16* __restrict__ Vb)
{
  const int n0g = blockIdx.x * BN;
  const int z   = n0g >> 10;
  const int n0  = n0g & 1023;
  const u16* W    = Wb + (size_t)z * ND * ND;
  const float* Bi = (z == 0) ? bq : (z == 1) ? bk : bv;
  u16* C          = (z == 0) ? Qb : (z == 1) ? Kb : Vb;
  const float sc  = (z == 0) ? QSCALE : 1.0f;

  const int m0 = blockIdx.y * BM;
  const int tid  = threadIdx.x;
  const int lane = tid & 63;
  const int wave = tid >> 6;
  const int wm = (wave >> 1) * 64;
  const int wn = (wave & 1) * 64;
  const int quad = lane >> 4;
  const int l16  = lane & 15;

  __shared__ u16 As[BM * LDT];
  __shared__ u16 Bs[BN * LDT];

  floatx4 acc[4][4];
#pragma unroll
  for (int i = 0; i < 4; ++i)
#pragma unroll
    for (int j = 0; j < 4; ++j)
      acc[i][j] = (floatx4){0.f, 0.f, 0.f, 0.f};

  for (int k0 = 0; k0 < ND; k0 += BK) {
#pragma unroll
    for (int it = 0; it < 2; ++it) {
      int idx = tid + it * 256;
      int rr  = idx >> 2;
      int c8  = (idx & 3) << 3;
      async_cp16(&Bs[idx * 8], &W[(size_t)(n0 + rr) * ND + k0 + c8]);
      async_cp16(&As[idx * 8], &A[(size_t)(m0 + rr) * ND + k0 + c8]);
    }
    __syncthreads();

    short8 af[4], bfr[4];
#pragma unroll
    for (int i = 0; i < 4; ++i)
      af[i] = *(const short8*)&As[(wm + i * 16 + l16) * LDT + quad * 8];
#pragma unroll
    for (int j = 0; j < 4; ++j)
      bfr[j] = *(const short8*)&Bs[(wn + j * 16 + l16) * LDT + quad * 8];

#pragma unroll
    for (int i = 0; i < 4; ++i)
#pragma unroll
      for (int j = 0; j < 4; ++j)
        acc[i][j] = __builtin_amdgcn_mfma_f32_16x16x32_bf16(af[i], bfr[j], acc[i][j], 0, 0, 0);
    __syncthreads();
  }

#pragma unroll
  for (int j = 0; j < 4; ++j) {
    const int ncol = n0 + wn + j * 16 + l16;
    const float bv2 = Bi[ncol];
#pragma unroll
    for (int i = 0; i < 4; ++i) {
      const int mbase = m0 + wm + i * 16 + quad * 4;
#pragma unroll
      for (int r2 = 0; r2 < 4; ++r2) {
        float v = (acc[i][j][r2] + bv2) * sc;
        C[(size_t)(mbase + r2) * ND + ncol] = f2bf(v);
      }
    }
  }
}

// ---------------------------------------------------------------------------
// Output projection GEMM (r11 proven form): BN=64, BK=32, 512 blocks.
// ---------------------------------------------------------------------------
#define BN2 64

__global__ __launch_bounds__(256)
void gemm_proj(const u16* __restrict__ A, const u16* __restrict__ W,
               const float* __restrict__ Bi, float* __restrict__ C)
{
  const int n0 = blockIdx.x * BN2;
  const int m0 = blockIdx.y * BM;
  const int tid  = threadIdx.x;
  const int lane = tid & 63;
  const int wave = tid >> 6;
  const int wm = (wave >> 1) * 64;
  const int wn = (wave & 1) * 32;
  const int quad = lane >> 4;
  const int l16  = lane & 15;

  __shared__ u16 As[BM * LDT];
  __shared__ u16 Bs[BN2 * LDT];

  floatx4 acc[4][2];
#pragma unroll
  for (int i = 0; i < 4; ++i)
#pragma unroll
    for (int j = 0; j < 2; ++j)
      acc[i][j] = (floatx4){0.f, 0.f, 0.f, 0.f};

  for (int k0 = 0; k0 < ND; k0 += BK) {
#pragma unroll
    for (int it = 0; it < 2; ++it) {
      int idx = tid + it * 256;
      int rr  = idx >> 2;
      int c8  = (idx & 3) << 3;
      async_cp16(&As[idx * 8], &A[(size_t)(m0 + rr) * ND + k0 + c8]);
    }
    {
      int rr = tid >> 2, c8 = (tid & 3) << 3;
      async_cp16(&Bs[tid * 8], &W[(size_t)(n0 + rr) * ND + k0 + c8]);
    }
    __syncthreads();

    short8 af[4], bfr[2];
#pragma unroll
    for (int i = 0; i < 4; ++i)
      af[i] = *(const short8*)&As[(wm + i * 16 + l16) * LDT + quad * 8];
#pragma unroll
    for (int j = 0; j < 2; ++j)
      bfr[j] = *(const short8*)&Bs[(wn + j * 16 + l16) * LDT + quad * 8];

#pragma unroll
    for (int i = 0; i < 4; ++i)
#pragma unroll
      for (int j = 0; j < 2; ++j)
        acc[i][j] = __builtin_amdgcn_mfma_f32_16x16x32_bf16(af[i], bfr[j], acc[i][j], 0, 0, 0);
    __syncthreads();
  }

#pragma unroll
  for (int j = 0; j < 2; ++j) {
    const int ncol = n0 + wn + j * 16 + l16;
    const float bv2 = Bi[ncol];
#pragma unroll
    for (int i = 0; i < 4; ++i) {
      const int mbase = m0 + wm + i * 16 + quad * 4;
#pragma unroll
      for (int r2 = 0; r2 < 4; ++r2)
        C[(size_t)(mbase + r2) * ND + ncol] = acc[i][j][r2] + bv2;
    }
  }
}

// ---------------------------------------------------------------------------
// V transpose: V [B,L,H,DH] -> VT [B,H,DH,L]. Coalesced 64x64 tiles via LDS.
// ---------------------------------------------------------------------------
#define TSTR 66
__global__ __launch_bounds__(256)
void vtrans(const u16* __restrict__ V, u16* __restrict__ VT)
{
  const int lt = blockIdx.x;
  const int bh = blockIdx.y;
  const int b = bh >> 4, h = bh & 15;
  const int l0 = lt * 64;
  const int tid = threadIdx.x;
  __shared__ u16 Ls[64][TSTR];
#pragma unroll
  for (int p = 0; p < 2; ++p) {
    int idx = tid + p * 256;
    int r = idx >> 3, c = (idx & 7) << 3;
    *(uint4*)&Ls[r][c] = *(const uint4*)&V[(size_t)(b * NL + l0 + r) * ND + h * NDH + c];
  }
  __syncthreads();
#pragma unroll
  for (int p = 0; p < 2; ++p) {
    int idx = tid + p * 256;
    int lg = idx & 7, d = idx >> 3;
    u16 tb[8];
#pragma unroll
    for (int e = 0; e < 8; ++e) tb[e] = Ls[lg * 8 + e][d];
    *(uint4*)&VT[((size_t)(b * NH + h) * NDH + d) * NL + l0 + lg * 8] = *(const uint4*)tb;
  }
}

// ---------------------------------------------------------------------------
// Split-K MFMA flash attention. No-max softmax => partial (O_unnorm, l) over
// disjoint key ranges ADD directly (no max rescaling) — so big tiles split.
//
// GRID 1536 = 6 rounds x 256 slots. Decode: r=t>>8, s=t&255, xcd=s&7,
// v=s>>3, bh_local=v&3, p=v>>2, bh=xcd*4+bh_local (4 heads/XCD, L2-resident).
//   r=0: qt=p      full [0..qt]          r=1: qt=15-p  full [0..qt]
//   r=2: qt=16+p   half0 [0..c0-1]       r=3: qt=31-p  half1 [c0..qt]
//   r=4: qt=31-p   half0 [0..c0-1]       r=5: qt=16+p  half1 [c0..qt]
// where c0=(qt+2)>>1. Per-CU chunk total = 17 + 49 = 66 EXACTLY for every
// slot; critical path <= 17 chunks (was 32). 6 blocks/CU (LDS 25.2KB*6=151KB).
// Full tiles normalize+write Y; halves write partial O (bf16) + l (fp32).
// ---------------------------------------------------------------------------
#define KC 64
#define PSTR 72

__global__ __launch_bounds__(256)
void attn_mfma(const u16* __restrict__ Q, const u16* __restrict__ K,
               const u16* __restrict__ VT, const int* __restrict__ msk,
               u16* __restrict__ Y, u16* __restrict__ PO, float* __restrict__ PL)
{
  const int t = blockIdx.x;
  const int r = t >> 8;            // 0..5
  const int s = t & 255;
  const int xcd = s & 7;
  const int v = s >> 3;            // 0..31
  const int bh = xcd * 4 + (v & 3);
  const int p = v >> 2;            // 0..7

  int qt, kc_lo, half = 0;
  bool partial;
  if (r == 0)      { qt = p;      kc_lo = 0;           partial = false; }
  else if (r == 1) { qt = 15 - p; kc_lo = 0;           partial = false; }
  else if (r == 2) { qt = 16 + p; kc_lo = 0;           partial = true; half = 0; }
  else if (r == 3) { qt = 31 - p; kc_lo = (qt + 2) >> 1; partial = true; half = 1; }
  else if (r == 4) { qt = 31 - p; kc_lo = 0;           partial = true; half = 0; }
  else             { qt = 16 + p; kc_lo = (qt + 2) >> 1; partial = true; half = 1; }
  const int kc_hi = (partial && half == 0) ? ((qt + 2) >> 1) - 1 : qt;

  const int b = bh >> 4;
  const int h = bh & 15;
  const int q0 = qt * 64;
  const int tid  = threadIdx.x;
  const int lane = tid & 63;
  const int wave = tid >> 6;
  const int wq   = wave * 16;
  const int quad = lane >> 4;
  const int l16  = lane & 15;

  __shared__ u16 Ks[KC * 64];      // [key][dim], chunk-swizzled
  __shared__ u16 Vt[NDH * 64];     // [dim][key], chunk-swizzled
  __shared__ u16 Ps[64][PSTR];     // [q_local][key]

  const u16* Kbase  = K  + (size_t)b * NL * ND + h * NDH;
  const u16* VTbase = VT + (size_t)(b * NH + h) * NDH * NL;
  const int* mbase  = msk + b * NL;

  // Q fragments (A-layout), pre-scaled by QSCALE in GEMM1.
  short8 qf[2];
#pragma unroll
  for (int kk = 0; kk < 2; ++kk)
    qf[kk] = *(const short8*)&Q[(size_t)(b * NL + q0 + wq + l16) * ND
                                + h * NDH + kk * 32 + quad * 8];

  short8 onesf;
  {
    const short ov = (l16 == 0) ? (short)0x3F80 : (short)0;
#pragma unroll
    for (int e = 0; e < 8; ++e) onesf[e] = ov;
  }

  floatx4 o[4];
#pragma unroll
  for (int ot = 0; ot < 4; ++ot) o[ot] = (floatx4){0.f, 0.f, 0.f, 0.f};
  floatx4 lacc = (floatx4){0.f, 0.f, 0.f, 0.f};

  const int odd = l16 & 1;
  const int sw  = l16 & 7;
  const int rowb = q0 + wq + quad * 4;

  auto chunk_body = [&](int k0, bool diag) {
#pragma unroll
    for (int pp = 0; pp < 2; ++pp) {
      int sl = tid + pp * 256;
      int rr = sl >> 3;
      int ch = (sl & 7) ^ (rr & 7);
      async_cp16(&Ks[sl * 8], Kbase + (size_t)(k0 + rr) * ND + ch * 8);
      async_cp16(&Vt[sl * 8], VTbase + (size_t)rr * NL + k0 + ch * 8);
    }
    __syncthreads();

    int mm[4];
#pragma unroll
    for (int ct = 0; ct < 4; ++ct) mm[ct] = mbase[k0 + ct * 16 + l16];

    floatx4 sc4[4];
#pragma unroll
    for (int ct = 0; ct < 4; ++ct) {
      const u16* krow = &Ks[(ct * 16 + l16) * 64];
      short8 kf0 = *(const short8*)(krow + ((quad ^ sw) << 3));
      short8 kf1 = *(const short8*)(krow + (((4 | quad) ^ sw) << 3));
      floatx4 a = (floatx4){0.f, 0.f, 0.f, 0.f};
      a = __builtin_amdgcn_mfma_f32_16x16x32_bf16(qf[0], kf0, a, 0, 0, 0);
      a = __builtin_amdgcn_mfma_f32_16x16x32_bf16(qf[1], kf1, a, 0, 0, 0);
      sc4[ct] = a;
    }

#pragma unroll
    for (int ct = 0; ct < 4; ++ct) {
      const float pmul = (float)mm[ct];
      float pv[4];
#pragma unroll
      for (int r2 = 0; r2 < 4; ++r2) {
        float pr = pmul * __builtin_amdgcn_exp2f(sc4[ct][r2]);
        if (diag) {
          const int col = k0 + ct * 16 + l16;
          pr = (col > rowb + r2) ? 0.f : pr;
        }
        pv[r2] = pr;
      }
      float nb0 = dpp_xor1_f(pv[0]), nb1 = dpp_xor1_f(pv[1]);
      float nb2 = dpp_xor1_f(pv[2]), nb3 = dpp_xor1_f(pv[3]);
      const int colb  = ct * 16 + (l16 & ~1);
      const int row01 = wq + quad * 4 + odd;
      unsigned d01 = odd ? pk_bf16(nb1, pv[1]) : pk_bf16(pv[0], nb0);
      unsigned d23 = odd ? pk_bf16(nb3, pv[3]) : pk_bf16(pv[2], nb2);
      *(unsigned*)&Ps[row01][colb]     = d01;
      *(unsigned*)&Ps[row01 + 2][colb] = d23;
    }

#pragma unroll
    for (int kk = 0; kk < 2; ++kk) {
      short8 pf = *(const short8*)&Ps[wq + l16][kk * 32 + quad * 8];
#pragma unroll
      for (int ot = 0; ot < 4; ++ot) {
        const u16* vrow = &Vt[(ot * 16 + l16) * 64];
        short8 vf = *(const short8*)(vrow + ((((kk << 2) | quad) ^ sw) << 3));
        o[ot] = __builtin_amdgcn_mfma_f32_16x16x32_bf16(pf, vf, o[ot], 0, 0, 0);
      }
      lacc = __builtin_amdgcn_mfma_f32_16x16x32_bf16(pf, onesf, lacc, 0, 0, 0);
    }
    __syncthreads();
  };

  for (int kc = kc_lo; kc < kc_hi; ++kc) chunk_body(kc * KC, false);
  chunk_body(kc_hi * KC, kc_hi == qt);

  if (!partial) {
    // normalize + write Y (aliases Q; our rows only, reads done)
    float inv[4];
#pragma unroll
    for (int r2 = 0; r2 < 4; ++r2) {
      const float l = __shfl(lacc[r2], quad << 4);
      inv[r2] = 1.0f / l;
    }
#pragma unroll
    for (int ot = 0; ot < 4; ++ot)
#pragma unroll
      for (int r2 = 0; r2 < 4; ++r2) {
        const int row = q0 + wq + quad * 4 + r2;
        Y[(size_t)(b * NL + row) * ND + h * NDH + ot * 16 + l16] = f2bf(o[ot][r2] * inv[r2]);
      }
  } else {
    // write raw partial: O bf16 (64x64) + l fp32 (64)
    const int slot = (bh * 16 + (qt - 16)) * 2 + half;
    u16* po = PO + (size_t)slot * 4096;
#pragma unroll
    for (int ot = 0; ot < 4; ++ot)
#pragma unroll
      for (int r2 = 0; r2 < 4; ++r2)
        po[(wq + quad * 4 + r2) * 64 + ot * 16 + l16] = f2bf(o[ot][r2]);
    if (l16 == 0) {
#pragma unroll
      for (int r2 = 0; r2 < 4; ++r2)
        PL[slot * 64 + wq + quad * 4 + r2] = lacc[r2];
    }
  }
}

// ---------------------------------------------------------------------------
// Combine: Y[row] = (O0 + O1) / (l0 + l1) for the split tiles (qt 16..31).
// 512 blocks x 256 threads; each thread handles 16 output elems.
// ---------------------------------------------------------------------------
__global__ __launch_bounds__(256)
void attn_combine(const u16* __restrict__ PO, const float* __restrict__ PL,
                  u16* __restrict__ Y)
{
  const int tt = blockIdx.x;          // 0..511
  const int bh = tt >> 4, qx = tt & 15, qt = 16 + qx;
  const int b = bh >> 4, h = bh & 15;
  const int tid = threadIdx.x;
  const int row = tid >> 2, cg = (tid & 3) << 4;
  const int sl0 = (bh * 16 + qx) * 2;
  const float l = PL[sl0 * 64 + row] + PL[(sl0 + 1) * 64 + row];
  const float inv = 1.0f / l;
  const u16* p0 = PO + (size_t)sl0 * 4096 + row * 64 + cg;
  const u16* p1 = p0 + 4096;
  u16* y = Y + (size_t)(b * NL + qt * 64 + row) * ND + h * NDH + cg;
  uint4 a0 = *(const uint4*)p0, a1 = *(const uint4*)(p0 + 8);
  uint4 b0 = *(const uint4*)p1, b1 = *(const uint4*)(p1 + 8);
  const u16* ap = (const u16*)&a0; const u16* bp = (const u16*)&b0;
  u16 outv[16];
#pragma unroll
  for (int e = 0; e < 8; ++e) outv[e] = f2bf((bf2f(ap[e]) + bf2f(bp[e])) * inv);
  ap = (const u16*)&a1; bp = (const u16*)&b1;
#pragma unroll
  for (int e = 0; e < 8; ++e) outv[8 + e] = f2bf((bf2f(ap[e]) + bf2f(bp[e])) * inv);
  *(uint4*)y = *(const uint4*)outv;
  *(uint4*)(y + 8) = *(const uint4*)(outv + 8);
}

// ---------------------------------------------------------------------------
extern "C" void kernel_launch(void* const* d_in, const int* in_sizes, int n_in,
                              void* d_out, int out_size, void* d_ws, size_t ws_size,
                              hipStream_t stream) {
  const float* x  = (const float*)d_in[0];
  const int*   m  = (const int*)d_in[1];
  const float* Wq = (const float*)d_in[2];
  const float* bq = (const float*)d_in[3];
  const float* Wk = (const float*)d_in[4];
  const float* bk = (const float*)d_in[5];
  const float* Wv = (const float*)d_in[6];
  const float* bv = (const float*)d_in[7];
  const float* Wp = (const float*)d_in[8];
  const float* bp = (const float*)d_in[9];
  float* out = (float*)d_out;

  // d_ws (32 MiB): Q|Y alias (8) + K (8) + V (8) + Wb (8).
  // d_out (16 MiB): xb (bf16 x, first 8 MiB; dead after gemm_qkv, then reused
  // as PO partial-O slots 1024x4096 bf16 = 8 MiB) + VTb (second 8 MiB).
  // PL (partial l, 256 KB) reuses Vb (dead after vtrans).
  const size_t per = (size_t)NM * ND;
  u16* Qb = (u16*)d_ws;
  u16* Kb = Qb + per;
  u16* Vb = Kb + per;
  u16* Wb = Vb + per;
  u16* Yb = Qb;                    // alias
  u16* xb = (u16*)d_out;
  u16* VTb = xb + per;
  u16* PO = xb;                    // reuses xb region after gemm_qkv
  float* PL = (float*)Vb;          // reuses Vb region after vtrans

  // 0) fp32 -> bf16 for weights and x
  cvt_all<<<2048, 256, 0, stream>>>(Wq, Wk, Wv, Wp, x, Wb, xb);

  // 1) QKV projections (Q pre-scaled by QSCALE)
  gemm_qkv<<<dim3(3 * ND / BN, NM / BM), 256, 0, stream>>>(
      xb, Wb, bq, bk, bv, Qb, Kb, Vb);

  // 1b) V -> VT
  vtrans<<<dim3(NL / 64, NB * NH), 256, 0, stream>>>(Vb, VTb);

  // 2) Split-K MFMA flash attention (full tiles -> Y; halves -> PO/PL)
  attn_mfma<<<1536, 256, 0, stream>>>(Qb, Kb, VTb, m, Yb, PO, PL);

  // 2b) Combine split-tile partials -> Y
  attn_combine<<<512, 256, 0, stream>>>(PO, PL, Yb);

  // 3) Output projection
  const u16* Wpb = Wb + 3 * (size_t)ND * ND;
  gemm_proj<<<dim3(ND / BN2, NM / BM), 256, 0, stream>>>(Yb, Wpb, bp, out);
}